// Round 6
// baseline (5903.340 us; speedup 1.0000x reference)
//
#include <hip/hip_runtime.h>
#include <hip/hip_bf16.h>

// GraphCastEdgeBlock fused persistent kernel for MI355X (gfx950).
// h = silu(LN(concat(ea, ns[src], nd[dst]) @ W1 + b1)); out = ea + h @ W2 + b2
// E=600000, N=50000, D=128, H=512, in=384. fp32 I/O; bf16 MFMA compute.
// Persistent 512 blocks (2/CU), MT=32. x staged as f32 via global_load_lds
// (async, zero staging regs), XOR-swizzled SoA regions; act [32][256] bf16
// half-buffer reused across two GEMM2 passes; raw barriers keep prefetch
// vmcnt outstanding across the tile.

#define E_TOTAL 600000
#define DD      128
#define HH      512
#define IND     384
#define MT      32
#define NT      18750   // E_TOTAL / MT
#define NBLK    512     // persistent blocks (2 per CU)

typedef __attribute__((ext_vector_type(8))) short bf16x8;
typedef __attribute__((ext_vector_type(4))) float f32x4;

__device__ __forceinline__ ushort f2bf(float f) {
    __hip_bfloat16 b = __float2bfloat16(f);
    return *reinterpret_cast<ushort*>(&b);
}

// async global->LDS, 16B per lane; LDS dest must be wave-uniform base
__device__ __forceinline__ void gl_lds16(const float* g, float* l) {
    __builtin_amdgcn_global_load_lds(
        (const __attribute__((address_space(1))) void*)g,
        (__attribute__((address_space(3))) void*)l, 16, 0, 0);
}

// raw barrier: drain LDS ops only, keep vmcnt (prefetch) outstanding
__device__ __forceinline__ void bar_lgkm() {
    asm volatile("s_waitcnt lgkmcnt(0)" ::: "memory");
    __builtin_amdgcn_sched_barrier(0);
    __builtin_amdgcn_s_barrier();
    __builtin_amdgcn_sched_barrier(0);
}

template <int CTRL>
__device__ __forceinline__ float dpp_add(float x) {
    union { float f; int i; } a, b;
    a.f = x;
    b.i = __builtin_amdgcn_update_dpp(0, a.i, CTRL, 0xf, 0xf, true);
    return x + b.f;
}
__device__ __forceinline__ float row16_sum(float s) {
    s = dpp_add<0xB1>(s);    // quad_perm xor1
    s = dpp_add<0x4E>(s);    // quad_perm xor2
    s = dpp_add<0x124>(s);   // row_ror:4
    s = dpp_add<0x128>(s);   // row_ror:8
    return s;
}

// W1 [384][512] f32 -> W1t [512][384] bf16 ; W2 [512][128] f32 -> W2t [128][512] bf16
__global__ void prep_weights(const float* __restrict__ W1, const float* __restrict__ W2,
                             ushort* __restrict__ W1t, ushort* __restrict__ W2t) {
    int j = blockIdx.x * 256 + threadIdx.x;
    if (j < IND * HH) {
        int n = j / IND, k = j % IND;
        W1t[j] = f2bf(W1[k * HH + n]);
    }
    int j2 = j - IND * HH;
    if (j2 >= 0 && j2 < HH * DD) {
        int d2 = j2 / HH, k = j2 % HH;
        W2t[j2] = f2bf(W2[k * DD + d2]);
    }
}

// issue 6 global_load_lds per wave for tile starting at edge e0n
__device__ __forceinline__ void stage_issue(
    const float* ea, const float* ns, const float* nd,
    float* Xea, float* Xsr, float* Xds,
    int e0n, int w, int ro, int jp,
    int s0, int d0, int s1, int d1)
{
    #pragma unroll
    for (int p = 0; p < 2; ++p) {
        int row = w * 4 + 2 * p + ro;                  // per-lane (ro = lane>>5)
        int swz = (jp ^ ((row & 7) << 2)) * 4;         // inverse-swizzled source chunk
        int si = p ? s1 : s0;
        int di = p ? d1 : d0;
        gl_lds16(ea + (size_t)(e0n + row) * DD + swz, Xea + (w * 4 + 2 * p) * DD);
        gl_lds16(ns + (size_t)si * DD + swz,          Xsr + (w * 4 + 2 * p) * DD);
        gl_lds16(nd + (size_t)di * DD + swz,          Xds + (w * 4 + 2 * p) * DD);
    }
}

__global__ __launch_bounds__(512, 4) void edge_persistent_kernel(
    const float* __restrict__ edge_attr,
    const float* __restrict__ nsrc,
    const float* __restrict__ ndst,
    const int*   __restrict__ eidx,
    const float* __restrict__ b1,
    const float* __restrict__ g1,
    const float* __restrict__ be1,
    const float* __restrict__ b2,
    const ushort* __restrict__ W1t,
    const ushort* __restrict__ W2t,
    float* __restrict__ out)
{
    __shared__ __align__(16) float Xbuf[3 * MT * DD];   // 49152 B (EA|SRC|DST, swizzled)
    __shared__ __align__(16) ushort act[MT * 256];      // 16384 B (half of H, swizzled)
    __shared__ float red_s[MT][4];
    __shared__ float red_q[MT][4];
    __shared__ __align__(8) float stats2[MT][2];

    const int tid  = threadIdx.x;
    const int lane = tid & 63;
    const int w    = tid >> 6;
    const int g    = lane >> 4;
    const int li   = lane & 15;
    const int wm   = w >> 2;            // row-half 0/1
    const int wn   = w & 3;             // col-quarter 0..3
    const int ro   = lane >> 5;
    const int jp   = lane & 31;
    const int r0   = w * 4 + ro;

    float* Xea = Xbuf;
    float* Xsr = Xbuf + MT * DD;
    float* Xds = Xbuf + 2 * MT * DD;

    // hoisted per-lane constants
    float b1v[8], g1v[8], bev[8];
    #pragma unroll
    for (int ni = 0; ni < 8; ++ni) {
        int c = wn * 128 + ni * 16 + li;
        b1v[ni] = b1[c]; g1v[ni] = g1[c]; bev[ni] = be1[c];
    }
    const float b2v0 = b2[wn * 32 + li];
    const float b2v1 = b2[wn * 32 + 16 + li];
    const ushort* w1p = W1t + (size_t)(wn * 128 + li) * IND + g * 8;
    const ushort* w2p = W2t + (size_t)(wn * 32 + li) * HH + g * 8;

    // prologue: stage first tile
    {
        const int e0n = blockIdx.x * MT;
        int rA = e0n + r0, rB = rA + 2;
        int s0 = eidx[rA], d0 = eidx[E_TOTAL + rA];
        int s1 = eidx[rB], d1 = eidx[E_TOTAL + rB];
        stage_issue(edge_attr, nsrc, ndst, Xea, Xsr, Xds, e0n, w, ro, jp, s0, d0, s1, d1);
    }

    for (int t = blockIdx.x; t < NT; t += NBLK) {
        __syncthreads();                 // drains prefetch: x(t) ready in LDS

        const int e0 = t * MT;
        const int tn = t + NBLK;
        const bool hn = (tn < NT);
        int s0n = 0, d0n = 0, s1n = 0, d1n = 0;
        if (hn) {                        // next-tile indices (land during GEMM1)
            int rA = tn * MT + r0, rB = rA + 2;
            s0n = eidx[rA]; d0n = eidx[E_TOTAL + rA];
            s1n = eidx[rB]; d1n = eidx[E_TOTAL + rB];
        }

        // ---- GEMM1: rows wm*16+li, cols wn*128 + ni*16+li, k = 384 ----
        f32x4 acc[8];
        #pragma unroll
        for (int ni = 0; ni < 8; ++ni) acc[ni] = (f32x4){0.f, 0.f, 0.f, 0.f};

        const int arow = wm * 16 + li;
        const int xl = (li & 7) << 2;
        #pragma unroll
        for (int kb = 0; kb < 12; ++kb) {
            const float* Xr = Xbuf + (kb >> 2) * (MT * DD) + arow * DD;
            int c0 = ((((kb & 3) * 8 + g * 2) ^ xl)) * 4;   // float offset of 32B chunk pair
            f32x4 lo = *(const f32x4*)(Xr + c0);
            f32x4 hi = *(const f32x4*)(Xr + c0 + 4);
            bf16x8 a;
            a[0] = (short)f2bf(lo[0]); a[1] = (short)f2bf(lo[1]);
            a[2] = (short)f2bf(lo[2]); a[3] = (short)f2bf(lo[3]);
            a[4] = (short)f2bf(hi[0]); a[5] = (short)f2bf(hi[1]);
            a[6] = (short)f2bf(hi[2]); a[7] = (short)f2bf(hi[3]);
            #pragma unroll
            for (int nh = 0; nh < 2; ++nh) {
                bf16x8 Bf[4];
                #pragma unroll
                for (int j = 0; j < 4; ++j)
                    Bf[j] = *(const bf16x8*)(w1p + (size_t)(nh * 4 + j) * 16 * IND + kb * 32);
                __builtin_amdgcn_s_setprio(1);
                #pragma unroll
                for (int j = 0; j < 4; ++j)
                    acc[nh * 4 + j] = __builtin_amdgcn_mfma_f32_16x16x32_bf16(
                        a, Bf[j], acc[nh * 4 + j], 0, 0, 0);
                __builtin_amdgcn_s_setprio(0);
            }
        }

        // ---- residual copy from EA LDS (before prefetch overwrites X) ----
        float ear[8];
        #pragma unroll
        for (int ni2 = 0; ni2 < 2; ++ni2)
            #pragma unroll
            for (int reg = 0; reg < 4; ++reg) {
                int row = wm * 16 + g * 4 + reg;
                int col = wn * 32 + ni2 * 16 + li;
                int ch = (col >> 2) ^ ((row & 7) << 2);
                ear[ni2 * 4 + reg] = Xea[row * DD + ch * 4 + (col & 3)];
            }

        // ---- bias + row stats (DPP 16-lane reduce, partials to LDS) ----
        #pragma unroll
        for (int reg = 0; reg < 4; ++reg) {
            float s = 0.f, q = 0.f;
            #pragma unroll
            for (int ni = 0; ni < 8; ++ni) {
                float h = acc[ni][reg] + b1v[ni];
                acc[ni][reg] = h;
                s += h;
                q = fmaf(h, h, q);
            }
            s = row16_sum(s);
            q = row16_sum(q);
            if (li == 0) {
                int row = wm * 16 + g * 4 + reg;
                red_s[row][wn] = s;
                red_q[row][wn] = q;
            }
        }
        bar_lgkm();   // B: x reads + partials done

        // prefetch next tile into X (async; in flight until next __syncthreads)
        if (hn)
            stage_issue(edge_attr, nsrc, ndst, Xea, Xsr, Xds,
                        tn * MT, w, ro, jp, s0n, d0n, s1n, d1n);

        if (tid < MT) {
            float s = red_s[tid][0] + red_s[tid][1] + red_s[tid][2] + red_s[tid][3];
            float q = red_q[tid][0] + red_q[tid][1] + red_q[tid][2] + red_q[tid][3];
            float mu  = s * (1.f / 512.f);
            float var = q * (1.f / 512.f) - mu * mu;
            stats2[tid][0] = mu;
            stats2[tid][1] = rsqrtf(var + 1e-5f);
        }
        bar_lgkm();   // C: stats ready

        float st_mu[4], st_rs[4];
        #pragma unroll
        for (int reg = 0; reg < 4; ++reg) {
            int row = wm * 16 + g * 4 + reg;
            st_mu[reg] = stats2[row][0];
            st_rs[reg] = stats2[row][1];
        }

        // ---- LN+SiLU half 1 (cols 0..255 = waves wn<2) -> act ----
        if (wn < 2) {
            #pragma unroll
            for (int reg = 0; reg < 4; ++reg) {
                int row = wm * 16 + g * 4 + reg;
                #pragma unroll
                for (int ni = 0; ni < 8; ++ni) {
                    float sc = st_rs[reg] * g1v[ni];
                    float tc = fmaf(-st_mu[reg], sc, bev[ni]);
                    float xn = fmaf(acc[ni][reg], sc, tc);
                    float av = xn * __builtin_amdgcn_rcpf(1.f + __expf(-xn));
                    int lcol = wn * 128 + ni * 16 + li;
                    act[row * 256 + (((lcol >> 3) ^ (row & 7)) << 3) + (lcol & 7)] = f2bf(av);
                }
            }
        }
        bar_lgkm();   // D: act-h1 ready

        // ---- GEMM2 pass 1 (k 0..255): rows wm*16+li, out cols wn*32 + ni2*16+li ----
        f32x4 acc2[2];
        acc2[0] = (f32x4){0.f, 0.f, 0.f, 0.f};
        acc2[1] = (f32x4){0.f, 0.f, 0.f, 0.f};
        #pragma unroll
        for (int kb = 0; kb < 8; ++kb) {
            int ch = (((kb * 4 + g) ^ (li & 7))) << 3;
            bf16x8 a2 = *(const bf16x8*)&act[(wm * 16 + li) * 256 + ch];
            bf16x8 B0 = *(const bf16x8*)(w2p + kb * 32);
            bf16x8 B1f = *(const bf16x8*)(w2p + (size_t)16 * HH + kb * 32);
            __builtin_amdgcn_s_setprio(1);
            acc2[0] = __builtin_amdgcn_mfma_f32_16x16x32_bf16(a2, B0, acc2[0], 0, 0, 0);
            acc2[1] = __builtin_amdgcn_mfma_f32_16x16x32_bf16(a2, B1f, acc2[1], 0, 0, 0);
            __builtin_amdgcn_s_setprio(0);
        }
        bar_lgkm();   // E: pass-1 act reads done

        // ---- LN+SiLU half 2 (cols 256..511 = waves wn>=2) -> act (reuse) ----
        if (wn >= 2) {
            #pragma unroll
            for (int reg = 0; reg < 4; ++reg) {
                int row = wm * 16 + g * 4 + reg;
                #pragma unroll
                for (int ni = 0; ni < 8; ++ni) {
                    float sc = st_rs[reg] * g1v[ni];
                    float tc = fmaf(-st_mu[reg], sc, bev[ni]);
                    float xn = fmaf(acc[ni][reg], sc, tc);
                    float av = xn * __builtin_amdgcn_rcpf(1.f + __expf(-xn));
                    int lcol = (wn - 2) * 128 + ni * 16 + li;
                    act[row * 256 + (((lcol >> 3) ^ (row & 7)) << 3) + (lcol & 7)] = f2bf(av);
                }
            }
        }
        bar_lgkm();   // F: act-h2 ready

        // ---- GEMM2 pass 2 (k 256..511) ----
        #pragma unroll
        for (int kb = 0; kb < 8; ++kb) {
            int ch = (((kb * 4 + g) ^ (li & 7))) << 3;
            bf16x8 a2 = *(const bf16x8*)&act[(wm * 16 + li) * 256 + ch];
            bf16x8 B0 = *(const bf16x8*)(w2p + (8 + kb) * 32);
            bf16x8 B1f = *(const bf16x8*)(w2p + (size_t)16 * HH + (8 + kb) * 32);
            __builtin_amdgcn_s_setprio(1);
            acc2[0] = __builtin_amdgcn_mfma_f32_16x16x32_bf16(a2, B0, acc2[0], 0, 0, 0);
            acc2[1] = __builtin_amdgcn_mfma_f32_16x16x32_bf16(a2, B1f, acc2[1], 0, 0, 0);
            __builtin_amdgcn_s_setprio(0);
        }

        // ---- epilogue: out = acc2 + b2 + ea (from regs) ----
        #pragma unroll
        for (int ni2 = 0; ni2 < 2; ++ni2)
            #pragma unroll
            for (int reg = 0; reg < 4; ++reg) {
                int row = wm * 16 + g * 4 + reg;
                size_t o = (size_t)(e0 + row) * DD + wn * 32 + ni2 * 16 + li;
                out[o] = acc2[ni2][reg] + (ni2 ? b2v1 : b2v0) + ear[ni2 * 4 + reg];
            }
    }
}

extern "C" void kernel_launch(void* const* d_in, const int* in_sizes, int n_in,
                              void* d_out, int out_size, void* d_ws, size_t ws_size,
                              hipStream_t stream) {
    const float* edge_attr = (const float*)d_in[0];
    const float* nsrc      = (const float*)d_in[1];
    const float* ndst      = (const float*)d_in[2];
    const int*   eidx      = (const int*)d_in[3];
    const float* W1        = (const float*)d_in[4];
    const float* b1        = (const float*)d_in[5];
    const float* g1        = (const float*)d_in[6];
    const float* be1       = (const float*)d_in[7];
    const float* W2        = (const float*)d_in[8];
    const float* b2        = (const float*)d_in[9];
    float* out = (float*)d_out;

    ushort* W1t = (ushort*)d_ws;             // 512*384 bf16 = 384 KiB
    ushort* W2t = W1t + IND * HH;            // 128*512 bf16 = 128 KiB

    hipLaunchKernelGGL(prep_weights,
                       dim3((IND * HH + HH * DD + 255) / 256), dim3(256), 0, stream,
                       W1, W2, W1t, W2t);

    hipLaunchKernelGGL(edge_persistent_kernel,
                       dim3(NBLK), dim3(512), 0, stream,
                       edge_attr, nsrc, ndst, eidx, b1, g1, be1, b2, W1t, W2t, out);
}

// Round 7
// 665.362 us; speedup vs baseline: 8.8724x; 8.8724x over previous
//
#include <hip/hip_runtime.h>
#include <hip/hip_bf16.h>

// GraphCastEdgeBlock fused kernel for MI355X (gfx950).
// h = silu(LN(concat(ea, ns[src], nd[dst]) @ W1 + b1)); out = ea + h @ W2 + b2
// E=600000, N=50000, D=128, H=512, in=384. fp32 I/O; bf16 MFMA compute.
// Round-4 structure (MTILE=64, 8 waves, grid 9375) with spill-free register
// budget (B2 ring-4), direct epilogue stores, hoisted gather indices.

#define E_TOTAL 600000
#define DD      128
#define HH      512
#define IND     384
#define MTILE   64
#define XS      520   // LDS row stride (bf16 elems); 1040 B

typedef __attribute__((ext_vector_type(8))) short bf16x8;
typedef __attribute__((ext_vector_type(4))) float f32x4;

__device__ __forceinline__ ushort f2bf(float f) {
    __hip_bfloat16 b = __float2bfloat16(f);
    return *reinterpret_cast<ushort*>(&b);
}

template <int CTRL>
__device__ __forceinline__ float dpp_add(float x) {
    union { float f; int i; } a, b;
    a.f = x;
    b.i = __builtin_amdgcn_update_dpp(0, a.i, CTRL, 0xf, 0xf, true);
    return x + b.f;
}
// sum across each 16-lane row (all lanes get the sum); pure VALU, no DS
__device__ __forceinline__ float row16_sum(float s) {
    s = dpp_add<0xB1>(s);    // quad_perm xor1
    s = dpp_add<0x4E>(s);    // quad_perm xor2
    s = dpp_add<0x124>(s);   // row_ror:4
    s = dpp_add<0x128>(s);   // row_ror:8
    return s;
}

// W1 [384][512] f32 -> W1t [512][384] bf16 ; W2 [512][128] f32 -> W2t [128][512] bf16
__global__ void prep_weights(const float* __restrict__ W1, const float* __restrict__ W2,
                             ushort* __restrict__ W1t, ushort* __restrict__ W2t) {
    int j = blockIdx.x * 256 + threadIdx.x;
    if (j < IND * HH) {
        int n = j / IND, k = j % IND;
        W1t[j] = f2bf(W1[k * HH + n]);
    }
    int j2 = j - IND * HH;
    if (j2 >= 0 && j2 < HH * DD) {
        int d2 = j2 / HH, k = j2 % HH;
        W2t[j2] = f2bf(W2[k * DD + d2]);
    }
}

__global__ __launch_bounds__(512, 4) void edge_block_kernel(
    const float* __restrict__ edge_attr,
    const float* __restrict__ nsrc,
    const float* __restrict__ ndst,
    const int*   __restrict__ eidx,
    const float* __restrict__ b1,
    const float* __restrict__ g1,
    const float* __restrict__ be1,
    const float* __restrict__ b2,
    const ushort* __restrict__ W1t,
    const ushort* __restrict__ W2t,
    float* __restrict__ out)
{
    __shared__ __align__(16) ushort xbuf[MTILE * XS];  // 66560 B (x, then act)
    __shared__ float red_s[MTILE][8];
    __shared__ float red_q[MTILE][8];
    __shared__ __align__(8) float stats[MTILE][2];

    const int tid  = threadIdx.x;
    const int e0   = blockIdx.x * MTILE;
    const int lane = tid & 63;
    const int w    = tid >> 6;          // wave 0..7
    const int g    = lane >> 4;         // quarter-wave 0..3
    const int li   = lane & 15;

    // ---- 1) stage x tile [64][384] -> LDS bf16; eidx hoisted for MLP ----
    {
        const int l32 = tid & 31, grp = tid >> 5;    // 16 groups of 32 lanes
        int si[4], di[4];
        #pragma unroll
        for (int it = 0; it < 4; ++it) {
            const int e = e0 + grp + it * 16;
            si[it] = eidx[e];
            di[it] = eidx[E_TOTAL + e];
        }
        #pragma unroll
        for (int it = 0; it < 4; ++it) {
            const int r = grp + it * 16;
            const int e = e0 + r;
            float4 ea = *(const float4*)&edge_attr[(size_t)e * DD + l32 * 4];
            float4 sf = *(const float4*)&nsrc[(size_t)si[it] * DD + l32 * 4];
            float4 df = *(const float4*)&ndst[(size_t)di[it] * DD + l32 * 4];
            ushort* row = &xbuf[r * XS];
            ushort4 ua = { f2bf(ea.x), f2bf(ea.y), f2bf(ea.z), f2bf(ea.w) };
            ushort4 us = { f2bf(sf.x), f2bf(sf.y), f2bf(sf.z), f2bf(sf.w) };
            ushort4 ud = { f2bf(df.x), f2bf(df.y), f2bf(df.z), f2bf(df.w) };
            *(ushort4*)&row[  0 + l32 * 4] = ua;
            *(ushort4*)&row[128 + l32 * 4] = us;
            *(ushort4*)&row[256 + l32 * 4] = ud;
        }
    }
    __syncthreads();   // A

    // ---- 2) GEMM1: h[64][512] = x @ W1; wave w owns cols [w*64, w*64+64) ----
    const int wn0 = w * 64;
    f32x4 acc[4][4];
    #pragma unroll
    for (int mi = 0; mi < 4; ++mi)
        #pragma unroll
        for (int ni = 0; ni < 4; ++ni)
            acc[mi][ni] = (f32x4){0.f, 0.f, 0.f, 0.f};

    const ushort* w1p = W1t + (size_t)(wn0 + li) * IND + g * 8;

    bf16x8 B1b[2][4];
    #pragma unroll
    for (int ni = 0; ni < 4; ++ni) B1b[0][ni] = *(const bf16x8*)(w1p + ni * 16 * IND);
    #pragma unroll
    for (int ni = 0; ni < 4; ++ni) B1b[1][ni] = *(const bf16x8*)(w1p + ni * 16 * IND + 32);

    #pragma unroll
    for (int kb = 0; kb < 12; ++kb) {
        const int cur = kb & 1;                  // compile-time after unroll
        const int ko  = kb * 32 + g * 8;
        bf16x8 a[4];
        #pragma unroll
        for (int mi = 0; mi < 4; ++mi)
            a[mi] = *(const bf16x8*)&xbuf[(mi * 16 + li) * XS + ko];
        __builtin_amdgcn_s_setprio(1);
        #pragma unroll
        for (int mi = 0; mi < 4; ++mi)
            #pragma unroll
            for (int ni = 0; ni < 4; ++ni)
                acc[mi][ni] = __builtin_amdgcn_mfma_f32_16x16x32_bf16(
                    a[mi], B1b[cur][ni], acc[mi][ni], 0, 0, 0);
        __builtin_amdgcn_s_setprio(0);
        if (kb < 10) {                           // prefetch depth 2
            #pragma unroll
            for (int ni = 0; ni < 4; ++ni)
                B1b[cur][ni] = *(const bf16x8*)(w1p + ni * 16 * IND + (kb + 2) * 32);
        }
    }

    // ---- 3) bias + row stats via DPP row-reduce ----
    float b1v[4], g1v[4], bev[4];
    #pragma unroll
    for (int ni = 0; ni < 4; ++ni) {
        int c = wn0 + ni * 16 + li;
        b1v[ni] = b1[c]; g1v[ni] = g1[c]; bev[ni] = be1[c];
    }

    #pragma unroll
    for (int mi = 0; mi < 4; ++mi) {
        #pragma unroll
        for (int reg = 0; reg < 4; ++reg) {
            float s = 0.f, q = 0.f;
            #pragma unroll
            for (int ni = 0; ni < 4; ++ni) {
                float h = acc[mi][ni][reg] + b1v[ni];
                acc[mi][ni][reg] = h;
                s += h;
                q = fmaf(h, h, q);
            }
            s = row16_sum(s);
            q = row16_sum(q);
            if (li == 0) {
                int row = mi * 16 + g * 4 + reg;
                red_s[row][w] = s;
                red_q[row][w] = q;
            }
        }
    }
    __syncthreads();   // B

    if (tid < MTILE) {
        float s = 0.f, q = 0.f;
        #pragma unroll
        for (int i = 0; i < 8; ++i) { s += red_s[tid][i]; q += red_q[tid][i]; }
        float mu  = s * (1.f / 512.f);
        float var = q * (1.f / 512.f) - mu * mu;
        stats[tid][0] = mu;
        stats[tid][1] = rsqrtf(var + 1e-5f);
    }
    __syncthreads();   // C

    // ---- 4) B2 ring-4 preload (16 VGPR only — no spills) ----
    const ushort* w2p = W2t + (size_t)(w * 16 + li) * HH + g * 8;
    bf16x8 B2r[4];
    #pragma unroll
    for (int i = 0; i < 4; ++i) B2r[i] = *(const bf16x8*)(w2p + i * 32);

    // ---- 5) LN + SiLU (folded affine, rcp silu) -> act bf16 in LDS ----
    #pragma unroll
    for (int mi = 0; mi < 4; ++mi) {
        #pragma unroll
        for (int reg = 0; reg < 4; ++reg) {
            int row = mi * 16 + g * 4 + reg;
            float2 st = *(float2*)&stats[row][0];     // {mu, rstd}
            #pragma unroll
            for (int ni = 0; ni < 4; ++ni) {
                float sc = st.y * g1v[ni];                       // rstd*gamma
                float tc = fmaf(-st.x, sc, bev[ni]);             // beta - mu*sc
                float xn = fmaf(acc[mi][ni][reg], sc, tc);
                float ex = __expf(-xn);
                float a  = xn * __builtin_amdgcn_rcpf(1.f + ex); // silu
                xbuf[row * XS + wn0 + ni * 16 + li] = f2bf(a);
            }
        }
    }
    __syncthreads();   // D

    // ---- residual loads issued early; latency hides under GEMM2 ----
    float ear[8];
    #pragma unroll
    for (int mi = 0; mi < 2; ++mi)
        #pragma unroll
        for (int reg = 0; reg < 4; ++reg) {
            int row = (mi * 2) * 16 + g * 4 + reg;     // rows for acc2[0],acc2[2] pattern below
            ear[mi * 4 + reg] = 0.f;                   // placeholder; real loads below
        }
    // actual: one residual per (mi,reg) of the 4x4 accumulator rows at col w*16+li
    float earr[4][4];
    #pragma unroll
    for (int mi = 0; mi < 4; ++mi)
        #pragma unroll
        for (int reg = 0; reg < 4; ++reg) {
            int row = mi * 16 + g * 4 + reg;
            earr[mi][reg] = edge_attr[(size_t)(e0 + row) * DD + w * 16 + li];
        }

    // ---- 6) GEMM2: out[64][128] = act @ W2; ring-4 streamed B ----
    f32x4 acc2[4];
    #pragma unroll
    for (int mi = 0; mi < 4; ++mi) acc2[mi] = (f32x4){0.f, 0.f, 0.f, 0.f};

    #pragma unroll
    for (int kb = 0; kb < 16; ++kb) {
        const int cur = kb & 3;                  // compile-time after unroll
        bf16x8 bf = B2r[cur];
        if (kb < 12)
            B2r[cur] = *(const bf16x8*)(w2p + (kb + 4) * 32);
        const int ko = kb * 32 + g * 8;
        bf16x8 a2[4];
        #pragma unroll
        for (int mi = 0; mi < 4; ++mi)
            a2[mi] = *(const bf16x8*)&xbuf[(mi * 16 + li) * XS + ko];
        __builtin_amdgcn_s_setprio(1);
        #pragma unroll
        for (int mi = 0; mi < 4; ++mi)
            acc2[mi] = __builtin_amdgcn_mfma_f32_16x16x32_bf16(a2[mi], bf, acc2[mi], 0, 0, 0);
        __builtin_amdgcn_s_setprio(0);
    }

    // ---- 7) epilogue: direct stores, out = acc2 + b2 + ea(regs) ----
    const float b2v = b2[w * 16 + li];
    #pragma unroll
    for (int mi = 0; mi < 4; ++mi) {
        #pragma unroll
        for (int reg = 0; reg < 4; ++reg) {
            int row = mi * 16 + g * 4 + reg;
            size_t o = (size_t)(e0 + row) * DD + w * 16 + li;
            out[o] = acc2[mi][reg] + b2v + earr[mi][reg];
        }
    }
    (void)ear;
}

extern "C" void kernel_launch(void* const* d_in, const int* in_sizes, int n_in,
                              void* d_out, int out_size, void* d_ws, size_t ws_size,
                              hipStream_t stream) {
    const float* edge_attr = (const float*)d_in[0];
    const float* nsrc      = (const float*)d_in[1];
    const float* ndst      = (const float*)d_in[2];
    const int*   eidx      = (const int*)d_in[3];
    const float* W1        = (const float*)d_in[4];
    const float* b1        = (const float*)d_in[5];
    const float* g1        = (const float*)d_in[6];
    const float* be1       = (const float*)d_in[7];
    const float* W2        = (const float*)d_in[8];
    const float* b2        = (const float*)d_in[9];
    float* out = (float*)d_out;

    ushort* W1t = (ushort*)d_ws;             // 512*384 bf16 = 384 KiB
    ushort* W2t = W1t + IND * HH;            // 128*512 bf16 = 128 KiB

    hipLaunchKernelGGL(prep_weights,
                       dim3((IND * HH + HH * DD + 255) / 256), dim3(256), 0, stream,
                       W1, W2, W1t, W2t);

    hipLaunchKernelGGL(edge_block_kernel,
                       dim3(E_TOTAL / MTILE), dim3(512), 0, stream,
                       edge_attr, nsrc, ndst, eidx, b1, g1, be1, b2, W1t, W2t, out);
}